// Round 7
// baseline (150651.660 us; speedup 1.0000x reference)
//
#include <hip/hip_runtime.h>

#define T_STEPS  8192
#define INPUT_N  256
#define OUTPUT_N 256
#define RES_N    4096
#define NB       256   // blocks (1 per CU)
#define NT       1024  // threads per block (16 waves)
#define RPB      16    // W_res rows per block

// Keep small per-thread constants (W_in col, W_out row chunk) from being
// re-loaded inside the loop.
#define PIN(x)  asm volatile("" : "+v"(x))
#define PIN4(v) do { PIN((v).x); PIN((v).y); PIN((v).z); PIN((v).w); } while (0)

typedef unsigned long long ull;

// fp32 -> bf16 round-to-nearest-even (inputs are finite; no NaN handling).
__device__ __forceinline__ unsigned bf16rne(float f) {
    const unsigned u = __float_as_uint(f);
    return (u + 0x7fffu + ((u >> 16) & 1u)) >> 16;
}
// bf16 (packed pair) -> fp32 is exact: low half shifted up / high half masked.
__device__ __forceinline__ float bflo(unsigned u) { return __uint_as_float(u << 16); }
__device__ __forceinline__ float bfhi(unsigned u) { return __uint_as_float(u & 0xffff0000u); }

// Persistent ESN kernel, LDS-resident bf16 W_res.
//
// Rounds 3-6 showed the register allocator will NOT give us >64 VGPRs at
// 1024 threads (launch_bounds/waves_per_eu both ignored), so 72 fp32
// weights/thread always spill to scratch (-> ~11 us/step reload). Instead:
// the block's 16x4096 W_res slice lives in LDS as bf16 (128 KB). Each
// weight is used once per step; LDS streams it at ~128 B/clk. The 149 KB
// LDS footprint also forces 1 block/CU -> the compiler's own budget is
// 128 VGPRs and the ~50-reg working set cannot spill.
//
// Decomposition: rg=tid>>8 owns rows rg*4..rg*4+3; cg=tid&255 owns state
// cols 8*(cg+256c), c=0,1 (two 8-wide chunks, lane-consecutive 16B -> all
// LDS reads conflict-free). Per step, 2 barriers:
//   stage (pollers tid<256: spin flag, load 16-float slice, 4x b128 write)
//   syncA
//   row partials (bf16 unpack + fma) + merged reduce4 -> lds_part
//   pred partial (W_out . state_{t-1}) -> lds_pp          [pre-C!]
//   syncC
//   wave15: combine+tanh+publish slice+flag (wave-local fence)
//   wave14: reduce lds_pp -> out[t-1]
__global__ __launch_bounds__(NT)
void esn_persistent(
    const float* __restrict__ X,       // [T, 256]
    const float* __restrict__ state0,  // [4096]
    const float* __restrict__ W_in,    // [4096, 256]
    const float* __restrict__ W_res,   // [4096, 4096]
    const float* __restrict__ W_out,   // [256, 4096]
    float* __restrict__ out,           // [T, 256]
    float* __restrict__ stbuf,         // ws: [2][4096]
    int*   __restrict__ flags)         // ws: [2][256], zeroed per call
{
    const int tid  = threadIdx.x;
    const int bid  = blockIdx.x;
    const int wid  = tid >> 6;          // wave 0..15
    const int lane = tid & 63;
    const int rg   = tid >> 8;          // row-group 0..3
    const int wg   = (tid >> 6) & 3;    // wave within row-group
    const int cg   = tid & 255;         // column group

    __shared__ unsigned short w_bf[RPB][RES_N];  // 128 KB bf16 weights
    __shared__ float lds_s[RES_N];               // 16 KB state_{t-1}
    __shared__ float lds_x[INPUT_N];             // 1 KB x_t
    __shared__ float lds_part[4][4][4];          // [rg][wg][r]
    __shared__ float lds_pp[16];                 // per-wave pred partials

    // ---- one-time: convert this block's W_res slice to bf16 in LDS ----
    float win[4];
#pragma unroll
    for (int r = 0; r < 4; ++r) {
        const int grow = bid * RPB + rg * 4 + r;
        const float* wr = W_res + (size_t)grow * RES_N;
#pragma unroll
        for (int c = 0; c < 2; ++c) {
            const int sb = 8 * (cg + 256 * c);
            const float4 a = *(const float4*)(wr + sb);
            const float4 b = *(const float4*)(wr + sb + 4);
            uint4 pk;
            pk.x = bf16rne(a.x) | (bf16rne(a.y) << 16);
            pk.y = bf16rne(a.z) | (bf16rne(a.w) << 16);
            pk.z = bf16rne(b.x) | (bf16rne(b.y) << 16);
            pk.w = bf16rne(b.z) | (bf16rne(b.w) << 16);
            *(uint4*)(&w_bf[rg * 4 + r][sb]) = pk;   // own chunk; read back by self
        }
        win[r] = W_in[(size_t)grow * INPUT_N + cg];
        PIN(win[r]);
    }
    float4 wout4 = *(const float4*)(W_out + (size_t)bid * RES_N + 4 * tid);
    PIN4(wout4);

    // x prefetch register (waves 4-7 own it)
    float xv = 0.f;
    if (tid >= 256 && tid < 512) xv = X[tid - 256];  // X[0]

#pragma unroll 1
    for (int t = 0; t <= T_STEPS; ++t) {
        const int par  = t & 1;
        const int ppar = (t + 1) & 1;

        // ---- stage state_{t-1} ----
        if (t == 0) {
            *(float4*)(lds_s + 4 * tid) = *(const float4*)(state0 + 4 * tid);
        } else if (tid < NB) {
            const int* f = flags + ppar * NB + tid;
            while (__hip_atomic_load(f, __ATOMIC_RELAXED,
                                     __HIP_MEMORY_SCOPE_AGENT) < t) { }
            (void)__hip_atomic_load(f, __ATOMIC_ACQUIRE, __HIP_MEMORY_SCOPE_AGENT);
            const ull* sp = (const ull*)(stbuf + (size_t)ppar * RES_N + tid * 16);
            ull q[8];
#pragma unroll
            for (int j = 0; j < 8; ++j)
                q[j] = __hip_atomic_load(sp + j, __ATOMIC_RELAXED,
                                         __HIP_MEMORY_SCOPE_AGENT);
            float* dst = lds_s + tid * 16;
#pragma unroll
            for (int k = 0; k < 4; ++k) {
                float4 v;
                v.x = __uint_as_float((unsigned)(q[2 * k] & 0xffffffffull));
                v.y = __uint_as_float((unsigned)(q[2 * k] >> 32));
                v.z = __uint_as_float((unsigned)(q[2 * k + 1] & 0xffffffffull));
                v.w = __uint_as_float((unsigned)(q[2 * k + 1] >> 32));
                *(float4*)(dst + 4 * k) = v;
            }
        }
        if (t < T_STEPS && tid >= 256 && tid < 512)
            lds_x[tid - 256] = xv;
        __syncthreads();  // A

        // prefetch next x (hidden under compute; drained at syncC)
        if (t + 1 < T_STEPS && tid >= 256 && tid < 512)
            xv = X[(size_t)(t + 1) * INPUT_N + (tid - 256)];

        // ---- row partials: 4 rows x 16 cols (2 chunks of 8) per thread ----
        if (t < T_STEPS) {
            float p[4] = {0.f, 0.f, 0.f, 0.f};
#pragma unroll
            for (int c = 0; c < 2; ++c) {
                const int sb = 8 * (cg + 256 * c);
                const float4 sa = *(const float4*)(lds_s + sb);
                const float4 sc = *(const float4*)(lds_s + sb + 4);
#pragma unroll
                for (int r = 0; r < 4; ++r) {
                    const uint4 w = *(const uint4*)(&w_bf[rg * 4 + r][sb]);
                    p[r] += bflo(w.x) * sa.x + bfhi(w.x) * sa.y
                          + bflo(w.y) * sa.z + bfhi(w.y) * sa.w
                          + bflo(w.z) * sc.x + bfhi(w.z) * sc.y
                          + bflo(w.w) * sc.z + bfhi(w.w) * sc.w;
                }
            }
            const float xvl = lds_x[cg];
            float p0 = p[0] + win[0] * xvl;
            float p1 = p[1] + win[1] * xvl;
            float p2 = p[2] + win[2] * xvl;
            float p3 = p[3] + win[3] * xvl;
            // merged reduce4: 2 butterfly levels on all four, select, 4 more
            p0 += __shfl_xor(p0, 1, 64); p1 += __shfl_xor(p1, 1, 64);
            p2 += __shfl_xor(p2, 1, 64); p3 += __shfl_xor(p3, 1, 64);
            p0 += __shfl_xor(p0, 2, 64); p1 += __shfl_xor(p1, 2, 64);
            p2 += __shfl_xor(p2, 2, 64); p3 += __shfl_xor(p3, 2, 64);
            float v = (lane & 1) ? ((lane & 2) ? p3 : p1)
                                 : ((lane & 2) ? p2 : p0);
            v += __shfl_xor(v, 4, 64);
            v += __shfl_xor(v, 8, 64);
            v += __shfl_xor(v, 16, 64);
            v += __shfl_xor(v, 32, 64);
            if (lane < 4) lds_part[rg][wg][lane] = v;  // lane r = row r sum
        }

        // ---- pred partial for state_{t-1} (pre-C: same-iter output) ----
        if (t > 0) {
            const float4 s4 = *(const float4*)(lds_s + 4 * tid);
            float pp = wout4.x * s4.x + wout4.y * s4.y
                     + wout4.z * s4.z + wout4.w * s4.w;
            pp += __shfl_xor(pp, 32, 64);
            pp += __shfl_xor(pp, 16, 64);
            pp += __shfl_xor(pp, 8, 64);
            pp += __shfl_xor(pp, 4, 64);
            pp += __shfl_xor(pp, 2, 64);
            pp += __shfl_xor(pp, 1, 64);
            if (lane == 0) lds_pp[wid] = pp;
        }
        __syncthreads();  // C

        // ---- wave 15: combine + tanh + publish slice + flag ----
        if (t < T_STEPS && wid == 15) {
            if (lane < RPB) {
                const int lrg = lane >> 2, lr = lane & 3;
                const float s = lds_part[lrg][0][lr] + lds_part[lrg][1][lr]
                              + lds_part[lrg][2][lr] + lds_part[lrg][3][lr];
                const float ns = tanhf(s);
                __hip_atomic_store(stbuf + (size_t)par * RES_N + bid * RPB + lane,
                                   ns, __ATOMIC_RELAXED, __HIP_MEMORY_SCOPE_AGENT);
            }
            __threadfence();  // wave-local: drains wave 15's 16 stores
            if (lane == 0)
                __hip_atomic_store(flags + par * NB + bid, t + 1,
                                   __ATOMIC_RELAXED, __HIP_MEMORY_SCOPE_AGENT);
        }

        // ---- wave 14: final pred reduce -> out[t-1] ----
        if (t > 0 && wid == 14 && lane < 16) {
            float pv = lds_pp[lane];
            pv += __shfl_xor(pv, 8, 64);
            pv += __shfl_xor(pv, 4, 64);
            pv += __shfl_xor(pv, 2, 64);
            pv += __shfl_xor(pv, 1, 64);
            if (lane == 0) out[(size_t)(t - 1) * OUTPUT_N + bid] = pv;
        }
    }
}

extern "C" void kernel_launch(void* const* d_in, const int* in_sizes, int n_in,
                              void* d_out, int out_size, void* d_ws, size_t ws_size,
                              hipStream_t stream) {
    const float* X      = (const float*)d_in[0];
    const float* state0 = (const float*)d_in[1];
    const float* W_in   = (const float*)d_in[2];
    const float* W_res  = (const float*)d_in[3];
    const float* W_out  = (const float*)d_in[4];
    float* out = (float*)d_out;

    float* stbuf = (float*)d_ws;                                     // 32 KiB
    int*   flags = (int*)((char*)d_ws + 2 * RES_N * sizeof(float));  // 2 KiB

    // Flags must start at 0 every call (ws is NOT re-poisoned between replays).
    (void)hipMemsetAsync(flags, 0, 2 * NB * sizeof(int), stream);

    esn_persistent<<<dim3(NB), dim3(NT), 0, stream>>>(
        X, state0, W_in, W_res, W_out, out, stbuf, flags);
}

// Round 8
// 66381.848 us; speedup vs baseline: 2.2695x; 2.2695x over previous
//
#include <hip/hip_runtime.h>

#define T_STEPS  8192
#define INPUT_N  256
#define OUTPUT_N 256
#define RES_N    4096
#define NB       256   // blocks (1 per CU)
#define NT       1024  // threads per block (16 waves)
#define RPB      16    // W_res rows per block

#define PIN(x)  asm volatile("" : "+v"(x))
#define PIN4(v) do { PIN((v).x); PIN((v).y); PIN((v).z); PIN((v).w); } while (0)

typedef unsigned long long ull;

// fp32 -> bf16 round-to-nearest-even (inputs are finite).
__device__ __forceinline__ unsigned bf16rne(float f) {
    const unsigned u = __float_as_uint(f);
    return (u + 0x7fffu + ((u >> 16) & 1u)) >> 16;
}
// bf16 (packed pair) -> fp32 is exact.
__device__ __forceinline__ float bflo(unsigned u) { return __uint_as_float(u << 16); }
__device__ __forceinline__ float bfhi(unsigned u) { return __uint_as_float(u & 0xffff0000u); }

// Persistent ESN kernel: LDS-resident bf16 W_res + MINIMAL-FENCE exchange.
//
// Protocol lesson (R6/R7 regression): agent-scope ACQUIRE loads emit
// buffer_inv (L2 invalidate) and __threadfence emits buffer_wbl2 (L2
// writeback) on gfx950 — both on the critical path, every step. Relaxed
// agent-scope atomics already bypass L2 (sc1) and are visible at the L3
// coherence point, so the only ordering needed is:
//   producer: relaxed slice stores -> s_waitcnt vmcnt(0) -> relaxed flag store
//   consumer: relaxed flag spin -> compiler barrier -> relaxed slice loads
// (R3-R5 ran exactly this visibility model correctly for 3 rounds.)
//
// Per step, 2 barriers:
//   pollers (tid<256): spin flag[tid], load block tid's 16-float slice, LDS
//   syncA
//   all: row partials (bf16 LDS weights) + merged reduce4 -> lds_part
//        pred partial (W_out . state_{t-1}) -> lds_pp
//   syncC
//   wave15: combine + tanh + publish slice (vmcnt(0)) + flag
//   wave14: reduce lds_pp -> out[t-1]
__global__ __launch_bounds__(NT)
void esn_persistent(
    const float* __restrict__ X,       // [T, 256]
    const float* __restrict__ state0,  // [4096]
    const float* __restrict__ W_in,    // [4096, 256]
    const float* __restrict__ W_res,   // [4096, 4096]
    const float* __restrict__ W_out,   // [256, 4096]
    float* __restrict__ out,           // [T, 256]
    float* __restrict__ stbuf,         // ws: [2][4096]
    int*   __restrict__ flags)         // ws: [2][256], zeroed per call
{
    const int tid  = threadIdx.x;
    const int bid  = blockIdx.x;
    const int wid  = tid >> 6;          // wave 0..15
    const int lane = tid & 63;
    const int rg   = tid >> 8;          // row-group 0..3
    const int wg   = (tid >> 6) & 3;    // wave within row-group
    const int cg   = tid & 255;         // column group

    __shared__ unsigned short w_bf[RPB][RES_N];  // 128 KB bf16 weights
    __shared__ float lds_s[RES_N];               // 16 KB state_{t-1}
    __shared__ float lds_x[INPUT_N];             // 1 KB x_t
    __shared__ float lds_part[4][4][4];          // [rg][wg][r]
    __shared__ float lds_pp[16];                 // per-wave pred partials

    // ---- one-time: this block's W_res slice -> bf16 in LDS ----
    float win[4];
#pragma unroll
    for (int r = 0; r < 4; ++r) {
        const int grow = bid * RPB + rg * 4 + r;
        const float* wr = W_res + (size_t)grow * RES_N;
#pragma unroll
        for (int c = 0; c < 2; ++c) {
            const int sb = 8 * (cg + 256 * c);
            const float4 a = *(const float4*)(wr + sb);
            const float4 b = *(const float4*)(wr + sb + 4);
            uint4 pk;
            pk.x = bf16rne(a.x) | (bf16rne(a.y) << 16);
            pk.y = bf16rne(a.z) | (bf16rne(a.w) << 16);
            pk.z = bf16rne(b.x) | (bf16rne(b.y) << 16);
            pk.w = bf16rne(b.z) | (bf16rne(b.w) << 16);
            *(uint4*)(&w_bf[rg * 4 + r][sb]) = pk;   // self-read-back chunk
        }
        win[r] = W_in[(size_t)grow * INPUT_N + cg];
        PIN(win[r]);
    }
    float4 wout4 = *(const float4*)(W_out + (size_t)bid * RES_N + 4 * tid);
    PIN4(wout4);

    // x prefetch register (waves 4-7 own it)
    float xv = 0.f;
    if (tid >= 256 && tid < 512) xv = X[tid - 256];  // X[0]

#pragma unroll 1
    for (int t = 0; t <= T_STEPS; ++t) {
        const int par  = t & 1;
        const int ppar = (t + 1) & 1;

        // ---- stage state_{t-1} ----
        if (t == 0) {
            *(float4*)(lds_s + 4 * tid) = *(const float4*)(state0 + 4 * tid);
        } else if (tid < NB) {
            const int* f = flags + ppar * NB + tid;
            while (__hip_atomic_load(f, __ATOMIC_RELAXED,
                                     __HIP_MEMORY_SCOPE_AGENT) < t) { }
            asm volatile("" ::: "memory");  // compiler-only: no cache ops
            const ull* sp = (const ull*)(stbuf + (size_t)ppar * RES_N + tid * 16);
            ull q[8];
#pragma unroll
            for (int j = 0; j < 8; ++j)
                q[j] = __hip_atomic_load(sp + j, __ATOMIC_RELAXED,
                                         __HIP_MEMORY_SCOPE_AGENT);
            float* dst = lds_s + tid * 16;
#pragma unroll
            for (int k = 0; k < 4; ++k) {
                float4 v;
                v.x = __uint_as_float((unsigned)(q[2 * k] & 0xffffffffull));
                v.y = __uint_as_float((unsigned)(q[2 * k] >> 32));
                v.z = __uint_as_float((unsigned)(q[2 * k + 1] & 0xffffffffull));
                v.w = __uint_as_float((unsigned)(q[2 * k + 1] >> 32));
                *(float4*)(dst + 4 * k) = v;
            }
        }
        if (t < T_STEPS && tid >= 256 && tid < 512)
            lds_x[tid - 256] = xv;
        __syncthreads();  // A

        // prefetch next x (normal cached load; X is read-only)
        if (t + 1 < T_STEPS && tid >= 256 && tid < 512)
            xv = X[(size_t)(t + 1) * INPUT_N + (tid - 256)];

        // ---- row partials: 4 rows x 16 cols (2 chunks of 8) per thread ----
        if (t < T_STEPS) {
            float p[4] = {0.f, 0.f, 0.f, 0.f};
#pragma unroll
            for (int c = 0; c < 2; ++c) {
                const int sb = 8 * (cg + 256 * c);
                const float4 sa = *(const float4*)(lds_s + sb);
                const float4 sc = *(const float4*)(lds_s + sb + 4);
#pragma unroll
                for (int r = 0; r < 4; ++r) {
                    const uint4 w = *(const uint4*)(&w_bf[rg * 4 + r][sb]);
                    p[r] += bflo(w.x) * sa.x + bfhi(w.x) * sa.y
                          + bflo(w.y) * sa.z + bfhi(w.y) * sa.w
                          + bflo(w.z) * sc.x + bfhi(w.z) * sc.y
                          + bflo(w.w) * sc.z + bfhi(w.w) * sc.w;
                }
            }
            const float xvl = lds_x[cg];
            float p0 = p[0] + win[0] * xvl;
            float p1 = p[1] + win[1] * xvl;
            float p2 = p[2] + win[2] * xvl;
            float p3 = p[3] + win[3] * xvl;
            p0 += __shfl_xor(p0, 1, 64); p1 += __shfl_xor(p1, 1, 64);
            p2 += __shfl_xor(p2, 1, 64); p3 += __shfl_xor(p3, 1, 64);
            p0 += __shfl_xor(p0, 2, 64); p1 += __shfl_xor(p1, 2, 64);
            p2 += __shfl_xor(p2, 2, 64); p3 += __shfl_xor(p3, 2, 64);
            float v = (lane & 1) ? ((lane & 2) ? p3 : p1)
                                 : ((lane & 2) ? p2 : p0);
            v += __shfl_xor(v, 4, 64);
            v += __shfl_xor(v, 8, 64);
            v += __shfl_xor(v, 16, 64);
            v += __shfl_xor(v, 32, 64);
            if (lane < 4) lds_part[rg][wg][lane] = v;  // lane r = row r sum
        }

        // ---- pred partial for state_{t-1} (same-iteration output) ----
        if (t > 0) {
            const float4 s4 = *(const float4*)(lds_s + 4 * tid);
            float pp = wout4.x * s4.x + wout4.y * s4.y
                     + wout4.z * s4.z + wout4.w * s4.w;
            pp += __shfl_xor(pp, 32, 64);
            pp += __shfl_xor(pp, 16, 64);
            pp += __shfl_xor(pp, 8, 64);
            pp += __shfl_xor(pp, 4, 64);
            pp += __shfl_xor(pp, 2, 64);
            pp += __shfl_xor(pp, 1, 64);
            if (lane == 0) lds_pp[wid] = pp;
        }
        __syncthreads();  // C

        // ---- wave 15: combine + tanh + publish slice + flag ----
        if (t < T_STEPS && wid == 15) {
            if (lane < RPB) {
                const int lrg = lane >> 2, lr = lane & 3;
                const float s = lds_part[lrg][0][lr] + lds_part[lrg][1][lr]
                              + lds_part[lrg][2][lr] + lds_part[lrg][3][lr];
                const float ns = tanhf(s);
                __hip_atomic_store(stbuf + (size_t)par * RES_N + bid * RPB + lane,
                                   ns, __ATOMIC_RELAXED, __HIP_MEMORY_SCOPE_AGENT);
            }
            // Wait for this wave's slice stores to reach the coherence point
            // (L3). No cache writeback/invalidate needed: stores are sc1.
            asm volatile("s_waitcnt vmcnt(0)" ::: "memory");
            if (lane == 0)
                __hip_atomic_store(flags + par * NB + bid, t + 1,
                                   __ATOMIC_RELAXED, __HIP_MEMORY_SCOPE_AGENT);
        }

        // ---- wave 14: final pred reduce -> out[t-1] ----
        if (t > 0 && wid == 14 && lane < 16) {
            float pv = lds_pp[lane];
            pv += __shfl_xor(pv, 8, 64);
            pv += __shfl_xor(pv, 4, 64);
            pv += __shfl_xor(pv, 2, 64);
            pv += __shfl_xor(pv, 1, 64);
            if (lane == 0) out[(size_t)(t - 1) * OUTPUT_N + bid] = pv;
        }
    }
}

extern "C" void kernel_launch(void* const* d_in, const int* in_sizes, int n_in,
                              void* d_out, int out_size, void* d_ws, size_t ws_size,
                              hipStream_t stream) {
    const float* X      = (const float*)d_in[0];
    const float* state0 = (const float*)d_in[1];
    const float* W_in   = (const float*)d_in[2];
    const float* W_res  = (const float*)d_in[3];
    const float* W_out  = (const float*)d_in[4];
    float* out = (float*)d_out;

    float* stbuf = (float*)d_ws;                                     // 32 KiB
    int*   flags = (int*)((char*)d_ws + 2 * RES_N * sizeof(float));  // 2 KiB

    // Flags must start at 0 every call (ws is NOT re-poisoned between replays).
    (void)hipMemsetAsync(flags, 0, 2 * NB * sizeof(int), stream);

    esn_persistent<<<dim3(NB), dim3(NT), 0, stream>>>(
        X, state0, W_in, W_res, W_out, out, stbuf, flags);
}

// Round 9
// 34017.709 us; speedup vs baseline: 4.4286x; 1.9514x over previous
//
#include <hip/hip_runtime.h>

#define T_STEPS  8192
#define INPUT_N  256
#define OUTPUT_N 256
#define RES_N    4096
#define NB       256   // blocks (1 per CU)
#define NT       1024  // threads per block (16 waves)
#define RPB      16    // W_res rows per block
#define FPAD     16    // dwords per flag slot (64 B) — kills L3 line hotspot

#define PIN(x) asm volatile("" : "+v"(x))

typedef unsigned long long ull;

// fp32 -> bf16 round-to-nearest-even (inputs finite).
__device__ __forceinline__ unsigned bf16rne(float f) {
    const unsigned u = __float_as_uint(f);
    return (u + 0x7fffu + ((u >> 16) & 1u)) >> 16;
}
__device__ __forceinline__ float bflo(unsigned u) { return __uint_as_float(u << 16); }
__device__ __forceinline__ float bfhi(unsigned u) { return __uint_as_float(u & 0xffff0000u); }

// Persistent ESN, fine-grained dataflow exchange.
//
// Thread map: wid=tid>>6, lane=tid&63, qg=lane>>2, rg=lane&3, cg=wid*16+qg.
// Thread owns rows bid*16+4rg+{0..3} and state cols {8cg..8cg+7} u
// {2048+8cg..+7}. Those 16 cols come from exactly 2 producer blocks, and the
// 4 lanes of a quad (same qg, rg=0..3) jointly need 4 quarter-slices -> each
// lane polls ONE padded flag, loads ONE 16B quarter (sc1, L2-bypassing),
// then 16 in-wave bpermutes assemble all 16 state floats per lane.
// No staging LDS, no pre-compute barrier.
//
// Weights: block's 16x4096 W_res slice in LDS as bf16 (128 KB), laid out
// [c][wid][r][lane][8] so every ds_read_b128 is a contiguous 1KB per wave
// (conflict-free). Pred (W_out row bid) reuses the same s16 registers on
// rg==0 lanes (each state col counted exactly once).
//
// Per step: poll+load+broadcast -> MAC+merged reduce -> lds_part / lds_pp
// -> syncthreads -> wave15: combine+tanh+publish slice+vmcnt(0)+flag;
//    wave14: reduce pred -> out[t-1].
// Cross-step lds reuse is safe: any foreign t+1 flag implies every block
// (incl. ours) consumed our t flag, which our wave15 set only after its
// t-combine read of lds_part.
__global__ __launch_bounds__(NT)
void esn_persistent(
    const float* __restrict__ X,       // [T, 256]
    const float* __restrict__ state0,  // [4096]
    const float* __restrict__ W_in,    // [4096, 256]
    const float* __restrict__ W_res,   // [4096, 4096]
    const float* __restrict__ W_out,   // [256, 4096]
    float* __restrict__ out,           // [T, 256]
    float* __restrict__ stbuf,         // ws: [2][4096]
    int*   __restrict__ flags)         // ws: [2][256][FPAD], zeroed per call
{
    const int tid  = threadIdx.x;
    const int bid  = blockIdx.x;
    const int wid  = tid >> 6;
    const int lane = tid & 63;
    const int qg   = lane >> 2;
    const int rg   = lane & 3;
    const int cg   = wid * 16 + qg;

    __shared__ unsigned short w_lds[2 * 16 * 4 * 64 * 8];  // 128 KB bf16
    __shared__ float lds_part[2][16][16];                   // [par][wid][slot]
    __shared__ float lds_pp[2][16];                         // [par][wid]

    // ---- one-time: weights ----
    float win[4];
#pragma unroll
    for (int r = 0; r < 4; ++r) {
        const int grow = bid * RPB + 4 * rg + r;
#pragma unroll
        for (int c = 0; c < 2; ++c) {
            const float* wr = W_res + (size_t)grow * RES_N + c * 2048 + 8 * cg;
            const float4 a = *(const float4*)wr;
            const float4 b = *(const float4*)(wr + 4);
            uint4 pk;
            pk.x = bf16rne(a.x) | (bf16rne(a.y) << 16);
            pk.y = bf16rne(a.z) | (bf16rne(a.w) << 16);
            pk.z = bf16rne(b.x) | (bf16rne(b.y) << 16);
            pk.w = bf16rne(b.z) | (bf16rne(b.w) << 16);
            ((uint4*)w_lds)[((c * 16 + wid) * 4 + r) * 64 + lane] = pk;
        }
        win[r] = W_in[(size_t)grow * INPUT_N + cg];
        PIN(win[r]);
    }
    float wo[16];
#pragma unroll
    for (int m = 0; m < 16; ++m) {
        const int col = (m < 8) ? (8 * cg + m) : (2048 + 8 * cg + (m - 8));
        wo[m] = W_out[(size_t)bid * RES_N + col];
        PIN(wo[m]);
    }

    // This lane's quarter-slice: source offset + producer flag.
    const int ofs_base = ((rg < 2) ? (8 * cg) : (2048 + 8 * cg)) + 4 * (rg & 1);
    const int myflag   = (rg < 2) ? (cg >> 1) : (128 + (cg >> 1));

    float xv = X[cg];  // x_0[cg]

#pragma unroll 1
    for (int t = 0; t <= T_STEPS; ++t) {
        const int par  = t & 1;
        const int ppar = (t + 1) & 1;

        // ---- acquire this lane's 16B quarter of state_{t-1} ----
        float4 q;
        if (t == 0) {
            q = *(const float4*)(state0 + ofs_base);
        } else {
            const int* f = flags + (ppar * NB + myflag) * FPAD;
            while (__hip_atomic_load(f, __ATOMIC_RELAXED,
                                     __HIP_MEMORY_SCOPE_AGENT) < t) { }
            asm volatile("" ::: "memory");  // compiler-only fence
            const ull* sp = (const ull*)(stbuf + (size_t)ppar * RES_N + ofs_base);
            const ull lo = __hip_atomic_load(sp, __ATOMIC_RELAXED,
                                             __HIP_MEMORY_SCOPE_AGENT);
            const ull hi = __hip_atomic_load(sp + 1, __ATOMIC_RELAXED,
                                             __HIP_MEMORY_SCOPE_AGENT);
            q.x = __uint_as_float((unsigned)lo);
            q.y = __uint_as_float((unsigned)(lo >> 32));
            q.z = __uint_as_float((unsigned)hi);
            q.w = __uint_as_float((unsigned)(hi >> 32));
        }

        // prefetch next x (plain cached load, hidden under shuffles/MAC)
        const float xn = X[(size_t)((t + 1 < T_STEPS) ? (t + 1) : 0) * INPUT_N + cg];

        // ---- in-wave broadcast: assemble all 16 state floats ----
        float s16[16];
#pragma unroll
        for (int j = 0; j < 4; ++j) {
            const int src = (lane & 0x3C) | j;
            s16[4 * j + 0] = __shfl(q.x, src, 64);
            s16[4 * j + 1] = __shfl(q.y, src, 64);
            s16[4 * j + 2] = __shfl(q.z, src, 64);
            s16[4 * j + 3] = __shfl(q.w, src, 64);
        }

        // ---- MAC: 4 rows x 16 cols, conflict-free b128 weight reads ----
        if (t < T_STEPS) {
            float p0 = win[0] * xv, p1 = win[1] * xv;
            float p2 = win[2] * xv, p3 = win[3] * xv;
#pragma unroll
            for (int c = 0; c < 2; ++c) {
                const int base = ((c * 16 + wid) * 4) * 64 + lane;
                const uint4 w0 = ((const uint4*)w_lds)[base];
                const uint4 w1 = ((const uint4*)w_lds)[base + 64];
                const uint4 w2 = ((const uint4*)w_lds)[base + 128];
                const uint4 w3 = ((const uint4*)w_lds)[base + 192];
                const float a0 = s16[c * 8 + 0], a1 = s16[c * 8 + 1];
                const float a2 = s16[c * 8 + 2], a3 = s16[c * 8 + 3];
                const float a4 = s16[c * 8 + 4], a5 = s16[c * 8 + 5];
                const float a6 = s16[c * 8 + 6], a7 = s16[c * 8 + 7];
                p0 += bflo(w0.x) * a0 + bfhi(w0.x) * a1 + bflo(w0.y) * a2
                    + bfhi(w0.y) * a3 + bflo(w0.z) * a4 + bfhi(w0.z) * a5
                    + bflo(w0.w) * a6 + bfhi(w0.w) * a7;
                p1 += bflo(w1.x) * a0 + bfhi(w1.x) * a1 + bflo(w1.y) * a2
                    + bfhi(w1.y) * a3 + bflo(w1.z) * a4 + bfhi(w1.z) * a5
                    + bflo(w1.w) * a6 + bfhi(w1.w) * a7;
                p2 += bflo(w2.x) * a0 + bfhi(w2.x) * a1 + bflo(w2.y) * a2
                    + bfhi(w2.y) * a3 + bflo(w2.z) * a4 + bfhi(w2.z) * a5
                    + bflo(w2.w) * a6 + bfhi(w2.w) * a7;
                p3 += bflo(w3.x) * a0 + bfhi(w3.x) * a1 + bflo(w3.y) * a2
                    + bfhi(w3.y) * a3 + bflo(w3.z) * a4 + bfhi(w3.z) * a5
                    + bflo(w3.w) * a6 + bfhi(w3.w) * a7;
            }
            // merged reduce over the 16 same-rg lanes (stride-4)
            p0 += __shfl_xor(p0, 4, 64); p1 += __shfl_xor(p1, 4, 64);
            p2 += __shfl_xor(p2, 4, 64); p3 += __shfl_xor(p3, 4, 64);
            p0 += __shfl_xor(p0, 8, 64); p1 += __shfl_xor(p1, 8, 64);
            p2 += __shfl_xor(p2, 8, 64); p3 += __shfl_xor(p3, 8, 64);
            float v = (qg & 1) ? ((qg & 2) ? p3 : p1)
                               : ((qg & 2) ? p2 : p0);
            v += __shfl_xor(v, 16, 64);
            v += __shfl_xor(v, 32, 64);
            if (lane < 16) lds_part[par][wid][lane] = v;  // row 4*(l&3)+(l>>2)
        }

        // ---- pred partial (rg==0 lanes own their 16 cols, counted once) ----
        if (t > 0) {
            float pp = 0.f;
            if (rg == 0) {
#pragma unroll
                for (int m = 0; m < 16; ++m) pp += wo[m] * s16[m];
            }
            pp += __shfl_xor(pp, 4, 64);
            pp += __shfl_xor(pp, 8, 64);
            pp += __shfl_xor(pp, 16, 64);
            pp += __shfl_xor(pp, 32, 64);
            if (lane == 0) lds_pp[par][wid] = pp;
        }
        __syncthreads();  // the only per-step barrier

        // ---- wave 15: combine + tanh + publish + flag ----
        if (t < T_STEPS && wid == 15) {
            if (lane < 16) {
                float acc = 0.f;
#pragma unroll
                for (int w = 0; w < 16; ++w) acc += lds_part[par][w][lane];
                const float ns = tanhf(acc);
                const int row = 4 * (lane & 3) + (lane >> 2);
                __hip_atomic_store(stbuf + (size_t)par * RES_N + bid * RPB + row,
                                   ns, __ATOMIC_RELAXED, __HIP_MEMORY_SCOPE_AGENT);
            }
            asm volatile("s_waitcnt vmcnt(0)" ::: "memory");  // slice at L3
            if (lane == 0)
                __hip_atomic_store(flags + (par * NB + bid) * FPAD, t + 1,
                                   __ATOMIC_RELAXED, __HIP_MEMORY_SCOPE_AGENT);
        }

        // ---- wave 14: pred reduce -> out[t-1] ----
        if (t > 0 && wid == 14 && lane < 16) {
            float pv = lds_pp[par][lane];
            pv += __shfl_xor(pv, 8, 64);
            pv += __shfl_xor(pv, 4, 64);
            pv += __shfl_xor(pv, 2, 64);
            pv += __shfl_xor(pv, 1, 64);
            if (lane == 0) out[(size_t)(t - 1) * OUTPUT_N + bid] = pv;
        }

        xv = xn;
    }
}

extern "C" void kernel_launch(void* const* d_in, const int* in_sizes, int n_in,
                              void* d_out, int out_size, void* d_ws, size_t ws_size,
                              hipStream_t stream) {
    const float* X      = (const float*)d_in[0];
    const float* state0 = (const float*)d_in[1];
    const float* W_in   = (const float*)d_in[2];
    const float* W_res  = (const float*)d_in[3];
    const float* W_out  = (const float*)d_in[4];
    float* out = (float*)d_out;

    float* stbuf = (float*)d_ws;                                     // 32 KiB
    int*   flags = (int*)((char*)d_ws + 2 * RES_N * sizeof(float));  // 32 KiB padded

    // Flags must start at 0 every call (ws is NOT re-poisoned between replays).
    (void)hipMemsetAsync(flags, 0, 2 * NB * FPAD * sizeof(int), stream);

    esn_persistent<<<dim3(NB), dim3(NT), 0, stream>>>(
        X, state0, W_in, W_res, W_out, out, stbuf, flags);
}

// Round 10
// 30871.701 us; speedup vs baseline: 4.8799x; 1.1019x over previous
//
#include <hip/hip_runtime.h>

#define T_STEPS  8192
#define INPUT_N  256
#define OUTPUT_N 256
#define RES_N    4096
#define NB       256   // blocks (1 per CU)
#define NT       1024  // threads per block (16 waves)
#define RPB      16    // rows per block

#define PIN(x) asm volatile("" : "+v"(x))

typedef unsigned long long ull;
typedef _Float16 half2v __attribute__((ext_vector_type(2)));

// f32x2 -> packed f16x2 (v_cvt_pkrtz_f16_f32), as raw dword.
__device__ __forceinline__ unsigned pkf16(float lo, float hi) {
    return __builtin_bit_cast(unsigned, __builtin_amdgcn_cvt_pkrtz(lo, hi));
}
// acc += dot(f16x2 w, f16x2 s)  (v_dot2_f32_f16, f32 accumulate)
__device__ __forceinline__ float fdot2(unsigned w, unsigned s, float acc) {
    return __builtin_amdgcn_fdot2(__builtin_bit_cast(half2v, w),
                                  __builtin_bit_cast(half2v, s), acc, false);
}

// Persistent ESN: f16 LDS weights + dot2 MAC + SELF-FLAGGING state exchange.
//
// State exchange: stbuf[2][4096] dwords; dword i of parity p =
// f16(state[i]) | (t+1)<<16 — the tag IS the flag. Consumer spins on its
// own 4 data dwords (min(tag) >= t); dword stores are atomic, tags are
// monotonic per buffer, and producers can't lap consumers (t+2 publish
// transitively requires all blocks consumed t+1). This removes the flag
// store + vmcnt + one L3 round-trip vs R9. stbuf memset per call (replay!).
//
// Thread map (R9): wid=tid>>6, lane=tid&63, qg=lane>>2, rg=lane&3,
// cg=wid*16+qg. Lane owns rows bid*16+4rg+{0..3}, loads ONE 16B quarter
// (4 tagged dwords), v_perm strips tags into 2 f16x2 pairs, 8 in-quad
// shuffles assemble all 8 state pairs. MAC: 4 rows x 8 fdot2 (weights
// f16x2 in LDS, 1KB/wave contiguous reads, conflict-free). Pred reuses
// the same pairs with f16x2 W_out on rg==0 lanes.
__global__ __launch_bounds__(NT)
void esn_persistent(
    const float* __restrict__ X,       // [T, 256]
    const float* __restrict__ state0,  // [4096]
    const float* __restrict__ W_in,    // [4096, 256]
    const float* __restrict__ W_res,   // [4096, 4096]
    const float* __restrict__ W_out,   // [256, 4096]
    float* __restrict__ out,           // [T, 256]
    unsigned* __restrict__ stbuf)      // ws: [2][4096] tagged, zeroed per call
{
    const int tid  = threadIdx.x;
    const int bid  = blockIdx.x;
    const int wid  = tid >> 6;
    const int lane = tid & 63;
    const int qg   = lane >> 2;
    const int rg   = lane & 3;
    const int cg   = wid * 16 + qg;

    __shared__ unsigned w_lds[2 * 16 * 4 * 64 * 4];  // 128 KB f16x2 weights
    __shared__ float lds_part[2][16][16];
    __shared__ float lds_pp[2][16];

    // ---- one-time: weights -> f16 pairs in LDS / registers ----
    float win[4];
#pragma unroll
    for (int r = 0; r < 4; ++r) {
        const int grow = bid * RPB + 4 * rg + r;
#pragma unroll
        for (int c = 0; c < 2; ++c) {
            const float* wr = W_res + (size_t)grow * RES_N + c * 2048 + 8 * cg;
            const float4 a = *(const float4*)wr;
            const float4 b = *(const float4*)(wr + 4);
            uint4 pk;
            pk.x = pkf16(a.x, a.y);
            pk.y = pkf16(a.z, a.w);
            pk.z = pkf16(b.x, b.y);
            pk.w = pkf16(b.z, b.w);
            ((uint4*)w_lds)[((c * 16 + wid) * 4 + r) * 64 + lane] = pk;
        }
        win[r] = W_in[(size_t)grow * INPUT_N + cg];
        PIN(win[r]);
    }
    unsigned wo[8];
#pragma unroll
    for (int m = 0; m < 8; ++m) {
        const int col = (m < 4) ? (8 * cg + 2 * m) : (2048 + 8 * cg + 2 * (m - 4));
        wo[m] = pkf16(W_out[(size_t)bid * RES_N + col],
                      W_out[(size_t)bid * RES_N + col + 1]);
        PIN(wo[m]);
    }

    // This lane's quarter-slice offset (4 consecutive state cols).
    const int ofs_base = ((rg < 2) ? (8 * cg) : (2048 + 8 * cg)) + 4 * (rg & 1);

    float xv = X[cg];  // x_0[cg]

#pragma unroll 1
    for (int t = 0; t <= T_STEPS; ++t) {
        const int par  = t & 1;
        const int ppar = (t + 1) & 1;

        // ---- acquire 4 tagged dwords of state_{t-1} ----
        unsigned d0, d1, d2, d3;
        if (t == 0) {
            const float4 q = *(const float4*)(state0 + ofs_base);
            d0 = pkf16(q.x, 0.f);
            d1 = pkf16(q.y, 0.f);
            d2 = pkf16(q.z, 0.f);
            d3 = pkf16(q.w, 0.f);
        } else {
            const unsigned exp = (unsigned)t;  // state_{t-1} tagged t
            const ull* sp = (const ull*)(stbuf + (size_t)ppar * RES_N + ofs_base);
            unsigned tmin;
            do {
                const ull lo = __hip_atomic_load(sp, __ATOMIC_RELAXED,
                                                 __HIP_MEMORY_SCOPE_AGENT);
                const ull hi = __hip_atomic_load(sp + 1, __ATOMIC_RELAXED,
                                                 __HIP_MEMORY_SCOPE_AGENT);
                d0 = (unsigned)lo; d1 = (unsigned)(lo >> 32);
                d2 = (unsigned)hi; d3 = (unsigned)(hi >> 32);
                tmin = min(min(d0 >> 16, d1 >> 16), min(d2 >> 16, d3 >> 16));
            } while (tmin < exp);
        }

        // prefetch next x (hidden under shuffles/MAC)
        const float xn = X[(size_t)((t + 1 < T_STEPS) ? (t + 1) : 0) * INPUT_N + cg];

        // ---- strip tags into f16x2 pairs, broadcast across the quad ----
        const unsigned pl0 = __builtin_amdgcn_perm(d1, d0, 0x05040100u);
        const unsigned pl1 = __builtin_amdgcn_perm(d3, d2, 0x05040100u);
        unsigned sp16[8];
#pragma unroll
        for (int m = 0; m < 8; ++m)
            sp16[m] = __shfl((m & 1) ? pl1 : pl0, (lane & 0x3C) | (m >> 1), 64);

        // ---- MAC: 4 rows x 8 dot2, conflict-free b128 weight reads ----
        if (t < T_STEPS) {
            float p0 = win[0] * xv, p1 = win[1] * xv;
            float p2 = win[2] * xv, p3 = win[3] * xv;
#pragma unroll
            for (int c = 0; c < 2; ++c) {
                const int base = ((c * 16 + wid) * 4) * 64 + lane;
                const uint4 w0 = ((const uint4*)w_lds)[base];
                const uint4 w1 = ((const uint4*)w_lds)[base + 64];
                const uint4 w2 = ((const uint4*)w_lds)[base + 128];
                const uint4 w3 = ((const uint4*)w_lds)[base + 192];
                const unsigned s0 = sp16[4 * c + 0], s1 = sp16[4 * c + 1];
                const unsigned s2 = sp16[4 * c + 2], s3 = sp16[4 * c + 3];
                p0 = fdot2(w0.x, s0, p0); p0 = fdot2(w0.y, s1, p0);
                p0 = fdot2(w0.z, s2, p0); p0 = fdot2(w0.w, s3, p0);
                p1 = fdot2(w1.x, s0, p1); p1 = fdot2(w1.y, s1, p1);
                p1 = fdot2(w1.z, s2, p1); p1 = fdot2(w1.w, s3, p1);
                p2 = fdot2(w2.x, s0, p2); p2 = fdot2(w2.y, s1, p2);
                p2 = fdot2(w2.z, s2, p2); p2 = fdot2(w2.w, s3, p2);
                p3 = fdot2(w3.x, s0, p3); p3 = fdot2(w3.y, s1, p3);
                p3 = fdot2(w3.z, s2, p3); p3 = fdot2(w3.w, s3, p3);
            }
            // merged reduce over the 16 same-rg lanes (stride-4)
            p0 += __shfl_xor(p0, 4, 64); p1 += __shfl_xor(p1, 4, 64);
            p2 += __shfl_xor(p2, 4, 64); p3 += __shfl_xor(p3, 4, 64);
            p0 += __shfl_xor(p0, 8, 64); p1 += __shfl_xor(p1, 8, 64);
            p2 += __shfl_xor(p2, 8, 64); p3 += __shfl_xor(p3, 8, 64);
            float v = (qg & 1) ? ((qg & 2) ? p3 : p1)
                               : ((qg & 2) ? p2 : p0);
            v += __shfl_xor(v, 16, 64);
            v += __shfl_xor(v, 32, 64);
            if (lane < 16) lds_part[par][wid][lane] = v;  // row 4*(l&3)+(l>>2)
        }

        // ---- pred partial for state_{t-1} (rg==0 lanes, dot2 on pairs) ----
        if (t > 0) {
            float pp = 0.f;
            if (rg == 0) {
#pragma unroll
                for (int m = 0; m < 8; ++m) pp = fdot2(wo[m], sp16[m], pp);
            }
            pp += __shfl_xor(pp, 4, 64);
            pp += __shfl_xor(pp, 8, 64);
            pp += __shfl_xor(pp, 16, 64);
            pp += __shfl_xor(pp, 32, 64);
            if (lane == 0) lds_pp[par][wid] = pp;
        }
        __syncthreads();  // the only per-step barrier

        // ---- wave 15: combine + tanh + publish tagged f16 state ----
        if (t < T_STEPS && wid == 15 && lane < 16) {
            float acc = 0.f;
#pragma unroll
            for (int w = 0; w < 16; ++w) acc += lds_part[par][w][lane];
            const float ns = tanhf(acc);
            const int row = 4 * (lane & 3) + (lane >> 2);
            const unsigned dw = pkf16(ns, 0.f) | ((unsigned)(t + 1) << 16);
            __hip_atomic_store(stbuf + (size_t)par * RES_N + bid * RPB + row,
                               dw, __ATOMIC_RELAXED, __HIP_MEMORY_SCOPE_AGENT);
            // no fence, no flag: the tag travels with the data
        }

        // ---- wave 14: pred reduce -> out[t-1] ----
        if (t > 0 && wid == 14 && lane < 16) {
            float pv = lds_pp[par][lane];
            pv += __shfl_xor(pv, 8, 64);
            pv += __shfl_xor(pv, 4, 64);
            pv += __shfl_xor(pv, 2, 64);
            pv += __shfl_xor(pv, 1, 64);
            if (lane == 0) out[(size_t)(t - 1) * OUTPUT_N + bid] = pv;
        }

        xv = xn;
    }
}

extern "C" void kernel_launch(void* const* d_in, const int* in_sizes, int n_in,
                              void* d_out, int out_size, void* d_ws, size_t ws_size,
                              hipStream_t stream) {
    const float* X      = (const float*)d_in[0];
    const float* state0 = (const float*)d_in[1];
    const float* W_in   = (const float*)d_in[2];
    const float* W_res  = (const float*)d_in[3];
    const float* W_out  = (const float*)d_in[4];
    float* out = (float*)d_out;

    unsigned* stbuf = (unsigned*)d_ws;  // 2*4096 tagged dwords = 32 KiB

    // Tags must start below any expected value every call (graph replays
    // reuse d_ws without re-poisoning; stale tags would satisfy the spin).
    (void)hipMemsetAsync(stbuf, 0, 2 * RES_N * sizeof(unsigned), stream);

    esn_persistent<<<dim3(NB), dim3(NT), 0, stream>>>(
        X, state0, W_in, W_res, W_out, out, stbuf);
}